// Round 3
// baseline (411.093 us; speedup 1.0000x reference)
//
#include <hip/hip_runtime.h>
#include <hip/hip_bf16.h>

typedef float f32x4 __attribute__((ext_vector_type(4)));
typedef __bf16 bf16x8 __attribute__((ext_vector_type(8)));
typedef __bf16 bf16x4 __attribute__((ext_vector_type(4)));

constexpr int B_ = 2, T_ = 2048, C_ = 2048, H_ = 16, D_ = 128;
constexpr int M_ = B_ * T_;        // 4096
constexpr int NQKV_ = 3 * C_;      // 6144

__device__ __forceinline__ void gload_lds16(const void* g, void* l) {
    __builtin_amdgcn_global_load_lds(
        (const __attribute__((address_space(1))) unsigned int*)g,
        (__attribute__((address_space(3))) unsigned int*)l,
        16, 0, 0);
}

// ---------------- fp32 -> bf16 convert (vectorized) ----------------
__global__ void cvt_kernel(const float* __restrict__ in, __bf16* __restrict__ out, int n4) {
    int i = blockIdx.x * blockDim.x + threadIdx.x;
    int stride = gridDim.x * blockDim.x;
    for (; i < n4; i += stride) {
        float4 v = reinterpret_cast<const float4*>(in)[i];
        bf16x4 o;
        o[0] = (__bf16)v.x; o[1] = (__bf16)v.y; o[2] = (__bf16)v.z; o[3] = (__bf16)v.w;
        reinterpret_cast<bf16x4*>(out)[i] = o;
    }
}

// ============ 8-phase 256-wide GEMM: C[M,N] = A[M,K] * B[N,K]^T ============
// BM in {128,256}, BN=256, BK=64, 512 threads (8 waves as 2Mx4N).
// Double-buffered LDS, chunk-XOR swizzle (chunk ^= row&7) applied on both the
// pre-swizzled global_load_lds SOURCE and the ds_read addresses (rule 21).
// Counted vmcnt(4) only at phases 4/8 (T4); raw s_barrier (no drain).

#define PHASE(bs, q, dowait, ...) do {                                                         \
    const char* Ab = Asb + (bs) * ABYTES;                                                      \
    const char* Bb = Bsb + (bs) * 32768;                                                       \
    bf16x8 af[QM][2];                                                                          \
    _Pragma("unroll") for (int mj = 0; mj < QM; ++mj) {                                        \
        int row = wrow + ((q) * QM + mj) * 16 + fr;                                            \
        _Pragma("unroll") for (int ks = 0; ks < 2; ++ks)                                       \
            af[mj][ks] = *reinterpret_cast<const bf16x8*>(                                     \
                Ab + row * 128 + (((ks * 4 + fq) ^ (row & 7)) << 4));                          \
    }                                                                                          \
    if ((q) == 0) {                                                                            \
        _Pragma("unroll") for (int n = 0; n < 4; ++n) {                                        \
            int row = wcol + n * 16 + fr;                                                      \
            _Pragma("unroll") for (int ks = 0; ks < 2; ++ks)                                   \
                bg[n][ks] = *reinterpret_cast<const bf16x8*>(                                  \
                    Bb + row * 128 + (((ks * 4 + fq) ^ (row & 7)) << 4));                      \
        }                                                                                      \
    }                                                                                          \
    __VA_ARGS__;                                                                               \
    __builtin_amdgcn_sched_barrier(0);                                                         \
    __builtin_amdgcn_s_barrier();                                                              \
    asm volatile("s_waitcnt lgkmcnt(0)" ::: "memory");                                         \
    __builtin_amdgcn_sched_barrier(0);                                                         \
    __builtin_amdgcn_s_setprio(1);                                                             \
    _Pragma("unroll") for (int mj = 0; mj < QM; ++mj)                                          \
        _Pragma("unroll") for (int n = 0; n < 4; ++n)                                          \
            _Pragma("unroll") for (int ks = 0; ks < 2; ++ks)                                   \
                acc[(q) * QM + mj][n] = __builtin_amdgcn_mfma_f32_16x16x32_bf16(               \
                    af[mj][ks], bg[n][ks], acc[(q) * QM + mj][n], 0, 0, 0);                    \
    __builtin_amdgcn_s_setprio(0);                                                             \
    if (dowait) { asm volatile("s_waitcnt vmcnt(4)" ::: "memory"); }                           \
    __builtin_amdgcn_sched_barrier(0);                                                         \
    __builtin_amdgcn_s_barrier();                                                              \
} while (0)

template <int BM, typename OutT>
__global__ __launch_bounds__(512, 2) void gemm8p(
    const __bf16* __restrict__ A, const __bf16* __restrict__ Bmat,
    OutT* __restrict__ Cm, int Mdim, int Ndim, int Kdim)
{
    constexpr int MFR = BM / 32;            // m-frags per wave
    constexpr int QM  = MFR / 4;            // m-frags per quadrant (phase)
    constexpr int ABYTES = BM * 64 * 2;
    __shared__ __align__(16) char Asb[2 * ABYTES];
    __shared__ __align__(16) char Bsb[2 * 32768];
    const int tid = threadIdx.x;
    const int w = tid >> 6, lane = tid & 63;
    const int fr = lane & 15, fq = lane >> 4;
    const int wm = w >> 2, wn = w & 3;
    const int wrow = wm * (BM / 2), wcol = wn * 64;
    const int NT = Kdim >> 6;               // K-tiles of 64
    const int NIT = Kdim >> 7;              // iterations (2 tiles each)
    const int nbx = Ndim >> 8;
    const int nwg = gridDim.x;
    int bid = (blockIdx.x & 7) * (nwg >> 3) + (blockIdx.x >> 3);  // XCD swizzle (nwg%8==0)
    const int bm = (bid / nbx) * BM;
    const int bn = (bid % nbx) << 8;
    const int srow8 = lane >> 3;
    const int scol = ((lane & 7) ^ srow8) << 3;   // pre-swizzled source chunk
    const int dst2k = w * 2048;

    f32x4 acc[MFR][4] = {};
    bf16x8 bg[4][2];

    auto stageB = [&](int db, int h, int t) {
        int tt = t < NT ? t : NT - 1;       // clamp: harmless re-stage, keeps vmcnt counts
        const __bf16* s0 = Bmat + (size_t)(bn + h * 128 + w * 16 + srow8) * Kdim + tt * 64 + scol;
        char* d = Bsb + db * 32768 + h * 16384 + dst2k;
        gload_lds16(s0, d);
        gload_lds16(s0 + (size_t)8 * Kdim, d + 1024);
    };
    auto stageA = [&](int db, int h, int t) {
        if (BM == 128 && h == 1) return;    // BM=128: A is a single 16KB unit
        int tt = t < NT ? t : NT - 1;
        const __bf16* s0 = A + (size_t)(bm + h * 128 + w * 16 + srow8) * Kdim + tt * 64 + scol;
        char* d = Asb + db * ABYTES + h * 16384 + dst2k;
        gload_lds16(s0, d);
        gload_lds16(s0 + (size_t)8 * Kdim, d + 1024);
    };

    // prologue: tile0 full -> buf0, tile1 B-halves -> buf1; leave 4 loads in flight
    stageB(0, 0, 0); stageB(0, 1, 0); stageA(0, 0, 0); stageA(0, 1, 0);
    stageB(1, 0, 1); stageB(1, 1, 1);
    asm volatile("s_waitcnt vmcnt(4)" ::: "memory");
    __builtin_amdgcn_sched_barrier(0);
    __builtin_amdgcn_s_barrier();

    for (int it = 0; it < NIT; ++it) {
        int t1 = 2 * it + 1, t2 = 2 * it + 2, t3 = 2 * it + 3;
        PHASE(0, 0, 0, stageA(1, 0, t1));                       // p1
        PHASE(0, 1, 0, stageA(1, 1, t1); stageB(0, 0, t2));     // p2
        PHASE(0, 2, 0, stageB(0, 1, t2));                       // p3
        PHASE(0, 3, 1, );                                       // p4 + vmcnt(4)
        PHASE(1, 0, 0, stageA(0, 0, t2));                       // p5
        PHASE(1, 1, 0, stageA(0, 1, t2));                       // p6
        PHASE(1, 2, 0, stageB(1, 0, t3));                       // p7
        PHASE(1, 3, 1, stageB(1, 1, t3));                       // p8 + vmcnt(4)
    }

    #pragma unroll
    for (int m = 0; m < MFR; ++m) {
        #pragma unroll
        for (int n = 0; n < 4; ++n) {
            int row0 = bm + wrow + m * 16 + fq * 4;
            int col = bn + wcol + n * 16 + fr;
            #pragma unroll
            for (int i = 0; i < 4; ++i)
                Cm[(size_t)(row0 + i) * Ndim + col] = (OutT)acc[m][n][i];
        }
    }
}

// ---------------- RoPE + pack qkv -> Q,K (B,H,T,D) rope'd, V (B,H,T,D) ----------------
__global__ void rope_pack(const __bf16* __restrict__ qkv,
                          const float* __restrict__ fcos, const float* __restrict__ fsin,
                          __bf16* __restrict__ Q, __bf16* __restrict__ K, __bf16* __restrict__ V)
{
    const int row = blockIdx.x;              // b*T + t
    const int b = row >> 11, t = row & (T_ - 1);
    const int tid = threadIdx.x;             // 256
    const int h = tid >> 4;
    const int jq = tid & 15;
    const float4 c4 = *reinterpret_cast<const float4*>(fcos + t * 64 + jq * 4);
    const float4 s4 = *reinterpret_cast<const float4*>(fsin + t * 64 + jq * 4);
    const float cc[4] = {c4.x, c4.y, c4.z, c4.w};
    const float ss[4] = {s4.x, s4.y, s4.z, s4.w};
    const __bf16* src = qkv + (size_t)row * NQKV_ + h * D_ + jq * 8;
    const size_t doff = ((size_t)(b * H_ + h) * T_ + t) * D_ + jq * 8;
    #pragma unroll
    for (int s = 0; s < 3; ++s) {
        bf16x8 v = *reinterpret_cast<const bf16x8*>(src + s * C_);
        bf16x8 o;
        if (s == 2) {
            o = v;
        } else {
            #pragma unroll
            for (int e = 0; e < 4; ++e) {
                float x0 = (float)v[2 * e], x1 = (float)v[2 * e + 1];
                o[2 * e]     = (__bf16)(x0 * cc[e] - x1 * ss[e]);
                o[2 * e + 1] = (__bf16)(x0 * ss[e] + x1 * cc[e]);
            }
        }
        __bf16* dst = (s == 0) ? Q : ((s == 1) ? K : V);
        *reinterpret_cast<bf16x8*>(dst + doff) = o;
    }
}

// ---------------- V (BH,T,D) -> Vt (BH,D,T), 64x64 LDS tiles ----------------
__global__ void transpose_v(const __bf16* __restrict__ V, __bf16* __restrict__ Vt) {
    const int bid = blockIdx.x;
    const int per_bh = (T_ / 64) * (D_ / 64);
    const int bh = bid / per_bh;
    const int rem = bid % per_bh;
    const int t0 = (rem / (D_ / 64)) * 64;
    const int d0 = (rem % (D_ / 64)) * 64;
    __shared__ __align__(16) __bf16 tile[64][72];
    const int tid = threadIdx.x;
    #pragma unroll
    for (int pass = 0; pass < 2; ++pass) {
        int r = pass * 32 + (tid >> 3);
        int ch = tid & 7;
        *reinterpret_cast<bf16x8*>(&tile[r][ch * 8]) =
            *reinterpret_cast<const bf16x8*>(V + ((size_t)bh * T_ + t0 + r) * D_ + d0 + ch * 8);
    }
    __syncthreads();
    #pragma unroll
    for (int pass = 0; pass < 2; ++pass) {
        int dr = pass * 32 + (tid >> 3);
        int ch = tid & 7;
        bf16x8 v;
        #pragma unroll
        for (int e = 0; e < 8; ++e) v[e] = tile[ch * 8 + e][dr];
        *reinterpret_cast<bf16x8*>(Vt + ((size_t)bh * D_ + d0 + dr) * T_ + t0 + ch * 8) = v;
    }
}

// ---------------- flash attention: QBLK=128, 4 waves x 32 rows, KVBLK=64, swapped QK^T ----------------
__global__ __launch_bounds__(256, 2) void attn_fwd(
    const __bf16* __restrict__ Q, const __bf16* __restrict__ K,
    const __bf16* __restrict__ Vt, __bf16* __restrict__ Out)
{
    const int bh = blockIdx.x;
    const int qt = (T_ / 128 - 1) - blockIdx.y;   // long blocks first
    const int tid = threadIdx.x;
    const int wave = tid >> 6, lane = tid & 63;
    const int fr = lane & 15, fq = lane >> 4;
    __shared__ __align__(16) __bf16 Ks[64 * 128];
    __shared__ __align__(16) __bf16 Vs[128 * 64];
    __shared__ __align__(16) __bf16 Ps[4][32 * 64];

    const int q0 = qt * 128 + wave * 32;
    bf16x8 qf[2][4];
    #pragma unroll
    for (int m = 0; m < 2; ++m)
        #pragma unroll
        for (int ks = 0; ks < 4; ++ks)
            qf[m][ks] = *reinterpret_cast<const bf16x8*>(
                Q + ((size_t)bh * T_ + q0 + m * 16 + fr) * D_ + ks * 32 + 8 * fq);

    f32x4 oacc[2][8] = {};
    float mrow[2] = {-3.0e38f, -3.0e38f}, lrow[2] = {0.f, 0.f};
    const float scale = 0.08838834764831845f;  // 1/sqrt(128)
    char* pb = (char*)&Ps[wave][0];
    const int qmax = q0 + 31;
    const int ktmax = 2 * qt + 1;
    const int kr = lane >> 4, kch = lane & 15;
    const int vr = lane >> 3, vch = lane & 7;

    for (int kt = 0; kt <= ktmax; ++kt) {
        __syncthreads();
        #pragma unroll
        for (int p = 0; p < 4; ++p) {
            int row = 16 * wave + 4 * p + kr;
            gload_lds16(K + ((size_t)bh * T_ + kt * 64 + row) * D_ + ((kch ^ (row & 7)) << 3),
                        (char*)Ks + (16 * wave + 4 * p) * 256);
        }
        #pragma unroll
        for (int p = 0; p < 4; ++p) {
            int row = 32 * wave + 8 * p + vr;
            gload_lds16(Vt + ((size_t)bh * D_ + row) * T_ + kt * 64 + ((vch ^ (row & 7)) << 3),
                        (char*)Vs + (32 * wave + 8 * p) * 128);
        }
        __syncthreads();
        if (kt * 64 > qmax) continue;

        f32x4 sacc[2][4] = {};
        __builtin_amdgcn_s_setprio(1);
        #pragma unroll
        for (int ks = 0; ks < 4; ++ks) {
            #pragma unroll
            for (int f = 0; f < 4; ++f) {
                int row = f * 16 + fr;
                bf16x8 kf = *reinterpret_cast<const bf16x8*>(
                    (const char*)Ks + row * 256 + (((ks * 4 + fq) ^ (fr & 7)) << 4));
                sacc[0][f] = __builtin_amdgcn_mfma_f32_16x16x32_bf16(kf, qf[0][ks], sacc[0][f], 0, 0, 0);
                sacc[1][f] = __builtin_amdgcn_mfma_f32_16x16x32_bf16(kf, qf[1][ks], sacc[1][f], 0, 0, 0);
            }
        }
        __builtin_amdgcn_s_setprio(0);

        const bool diag = (kt >= 2 * qt);
        #pragma unroll
        for (int m = 0; m < 2; ++m) {
            const int qg = q0 + m * 16 + fr;
            const int r = m * 16 + fr;
            float mx = -3.0e38f;
            #pragma unroll
            for (int f = 0; f < 4; ++f)
                #pragma unroll
                for (int i = 0; i < 4; ++i) {
                    float sv = sacc[m][f][i] * scale;
                    if (diag && (kt * 64 + f * 16 + fq * 4 + i) > qg) sv = -3.0e38f;
                    sacc[m][f][i] = sv;
                    mx = fmaxf(mx, sv);
                }
            mx = fmaxf(mx, __shfl_xor(mx, 16, 64));
            mx = fmaxf(mx, __shfl_xor(mx, 32, 64));
            float mn = fmaxf(mrow[m], mx);
            float al = __expf(mrow[m] - mn);
            mrow[m] = mn;
            float rs = 0.f;
            #pragma unroll
            for (int f = 0; f < 4; ++f) {
                bf16x4 pv;
                #pragma unroll
                for (int i = 0; i < 4; ++i) {
                    float p = __expf(sacc[m][f][i] - mn);
                    rs += p;
                    pv[i] = (__bf16)p;
                }
                *reinterpret_cast<bf16x4*>(pb + r * 128 + ((f * 32 + fq * 8) ^ ((fr & 7) << 4))) = pv;
            }
            rs += __shfl_xor(rs, 16, 64);
            rs += __shfl_xor(rs, 32, 64);
            lrow[m] = lrow[m] * al + rs;
            float av[4];
            #pragma unroll
            for (int i = 0; i < 4; ++i) av[i] = __shfl(al, fq * 4 + i, 16);
            #pragma unroll
            for (int n = 0; n < 8; ++n)
                #pragma unroll
                for (int i = 0; i < 4; ++i) oacc[m][n][i] *= av[i];
        }

        __builtin_amdgcn_s_setprio(1);
        #pragma unroll
        for (int ks = 0; ks < 2; ++ks) {
            bf16x8 pa[2];
            #pragma unroll
            for (int m = 0; m < 2; ++m) {
                int r = m * 16 + fr;
                pa[m] = *reinterpret_cast<const bf16x8*>(pb + r * 128 + ((ks * 64 + fq * 16) ^ ((fr & 7) << 4)));
            }
            #pragma unroll
            for (int n = 0; n < 8; ++n) {
                int d = n * 16 + fr;
                bf16x8 vf = *reinterpret_cast<const bf16x8*>(
                    (const char*)Vs + d * 128 + (((ks * 4 + fq) ^ (fr & 7)) << 4));
                oacc[0][n] = __builtin_amdgcn_mfma_f32_16x16x32_bf16(pa[0], vf, oacc[0][n], 0, 0, 0);
                oacc[1][n] = __builtin_amdgcn_mfma_f32_16x16x32_bf16(pa[1], vf, oacc[1][n], 0, 0, 0);
            }
        }
        __builtin_amdgcn_s_setprio(0);
    }

    const int b = bh >> 4, h = bh & 15;
    #pragma unroll
    for (int m = 0; m < 2; ++m) {
        float linv[4];
        #pragma unroll
        for (int i = 0; i < 4; ++i) linv[i] = 1.0f / __shfl(lrow[m], fq * 4 + i, 16);
        #pragma unroll
        for (int n = 0; n < 8; ++n) {
            int d = n * 16 + fr;
            #pragma unroll
            for (int i = 0; i < 4; ++i) {
                int tg = qt * 128 + wave * 32 + m * 16 + fq * 4 + i;
                Out[((size_t)b * T_ + tg) * C_ + h * D_ + d] = (__bf16)(oacc[m][n][i] * linv[i]);
            }
        }
    }
}

// ---------------- launch ----------------
extern "C" void kernel_launch(void* const* d_in, const int* in_sizes, int n_in,
                              void* d_out, int out_size, void* d_ws, size_t ws_size,
                              hipStream_t stream) {
    const float* x = (const float*)d_in[0];
    const float* w_qkv = (const float*)d_in[1];
    const float* w_proj = (const float*)d_in[2];
    const float* fcos = (const float*)d_in[3];
    const float* fsin = (const float*)d_in[4];
    float* out = (float*)d_out;

    char* ws = (char*)d_ws;
    size_t o = 0;
    __bf16* xb     = (__bf16*)(ws + o); o += (size_t)M_ * C_ * 2;
    __bf16* wqkvb  = (__bf16*)(ws + o); o += (size_t)NQKV_ * C_ * 2;
    __bf16* wprojb = (__bf16*)(ws + o); o += (size_t)C_ * C_ * 2;
    __bf16* qkvb   = (__bf16*)(ws + o); o += (size_t)M_ * NQKV_ * 2;
    __bf16* Qb     = (__bf16*)(ws + o); o += (size_t)M_ * C_ * 2;
    __bf16* Kb     = (__bf16*)(ws + o); o += (size_t)M_ * C_ * 2;
    __bf16* Vb     = wqkvb;   // alias: w_qkv bf16 dead after QKV GEMM
    __bf16* Vtb    = xb;      // alias: x bf16 dead after QKV GEMM
    __bf16* attnb  = qkvb;    // alias: qkv dead after rope_pack

    cvt_kernel<<<2048, 256, 0, stream>>>(x, xb, M_ * C_ / 4);
    cvt_kernel<<<2048, 256, 0, stream>>>(w_qkv, wqkvb, NQKV_ * C_ / 4);
    cvt_kernel<<<2048, 256, 0, stream>>>(w_proj, wprojb, C_ * C_ / 4);
    gemm8p<256, __bf16><<<(M_ / 256) * (NQKV_ / 256), 512, 0, stream>>>(xb, wqkvb, qkvb, M_, NQKV_, C_);
    rope_pack<<<M_, 256, 0, stream>>>(qkvb, fcos, fsin, Qb, Kb, Vb);
    transpose_v<<<B_ * H_ * (T_ / 64) * (D_ / 64), 256, 0, stream>>>(Vb, Vtb);
    attn_fwd<<<dim3(B_ * H_, T_ / 128), 256, 0, stream>>>(Qb, Kb, Vtb, attnb);
    gemm8p<128, float><<<(M_ / 128) * (C_ / 256), 512, 0, stream>>>(attnb, wprojb, out, M_, C_, C_);
}